// Round 8
// baseline (108.454 us; speedup 1.0000x reference)
//
#include <hip/hip_runtime.h>

typedef _Float16 f16;
typedef _Float16 f16x8 __attribute__((ext_vector_type(8)));
typedef float f32x4 __attribute__((ext_vector_type(4)));
typedef unsigned int u32;
typedef const __attribute__((address_space(1))) u32* gas1_t;
typedef __attribute__((address_space(3))) u32* las3_t;

#define WGRAN 460800   // 225 * 2048 granules of 8 halves (W)
#define IGRAN 32768    // 262144/8 granules (inp)

// fp32 -> f16 with W permuted into the fragment-ready layout:
// W_h[dxdy][i][o][quad] (granules of 8 halves) = W[dxdy][o][i][quad*8+u]
__global__ __launch_bounds__(256) void convert_kernel(
    const float* __restrict__ W, const float* __restrict__ inp,
    f16* __restrict__ W_h, f16* __restrict__ inp_h)
{
    const int g = blockIdx.x * 256 + threadIdx.x;   // grid sized exactly
    if (g < WGRAN) {
        const int dxdy = g >> 11;
        const int r = g & 2047;
        const int i = r >> 6, o = (r >> 2) & 15, quad = r & 3;
        const float* src = W + (size_t)dxdy * 16384 + o * 1024 + i * 32 + quad * 8;
        const float4 v0 = *(const float4*)src;
        const float4 v1 = *(const float4*)(src + 4);
        f16x8 h = { (f16)v0.x, (f16)v0.y, (f16)v0.z, (f16)v0.w,
                    (f16)v1.x, (f16)v1.y, (f16)v1.z, (f16)v1.w };
        *(f16x8*)(W_h + (size_t)g * 8) = h;
    } else {
        const int k = g - WGRAN;
        const float* src = inp + (size_t)k * 8;
        const float4 v0 = *(const float4*)src;
        const float4 v1 = *(const float4*)(src + 4);
        f16x8 h = { (f16)v0.x, (f16)v0.y, (f16)v0.z, (f16)v0.w,
                    (f16)v1.x, (f16)v1.y, (f16)v1.z, (f16)v1.w };
        *(f16x8*)(inp_h + (size_t)k * 8) = h;
    }
}

// One block per (x,y,X,Y), 256 thr = 4 waves. K-SPLIT: wave = (khalf, wset);
// wset selects b-tiles (4 per wave), khalf selects kb 0-15 / 16-31.
// Each bfrag ds_read_b128 now feeds 4 MFMA (was 2) -> LDS reads halved.
// Partials combined via 8 KB LDS exchange at the end.
__global__ __launch_bounds__(256, 5) void rel_mfma4(
    const f16* __restrict__ W_h,    // [dxdy][i][o][quad][8]
    const f16* __restrict__ inp_h,  // (128,8,8,32) f16
    const float* __restrict__ bias, // (15,15,16)
    float* __restrict__ out)        // (128,8,8,8,8,16)
{
    extern __shared__ __align__(16) f16 Wl[];   // 32768 B exactly

    const int bid = blockIdx.x;
    const int Y = bid & 7, X = (bid >> 3) & 7, y = (bid >> 6) & 7, x = (bid >> 9) & 7;
    const int dx = X - x + 7, dy = Y - y + 7;
    const int dxdy = dx * 15 + dy;

    const int t = threadIdx.x;

    // ---- stage W-block via global_load_lds width=16 ----
    {
        const f16* base = W_h + (size_t)dxdy * 16384;
        #pragma unroll
        for (int it = 0; it < 8; ++it) {
            const int idx = (it * 256 + t) * 8;          // 16 B granule
            __builtin_amdgcn_global_load_lds((gas1_t)(base + idx),
                                             (las3_t)&Wl[idx], 16, 0, 0);
        }
    }

    const int lane = t & 63;
    const int wave = t >> 6;        // 0..3
    const int wset = wave & 1;      // b-tile set: tiles 4*wset .. +3
    const int khalf = wave >> 1;    // kb half: 0 -> 0..15, 1 -> 16..31
    const int quad = lane >> 4;
    const int m = lane & 15;        // A-row (b%16) and B-col (o)

    // ---- a-rows (only this wave's K-half) + c-frags ----
    f16x8 a[4][2], c[4];
    #pragma unroll
    for (int tt = 0; tt < 4; ++tt) {
        const int b0 = (wset * 4 + tt) * 16 + m;
        const f16* ar = inp_h + ((b0 * 8 + x) * 8 + y) * 32 + khalf * 16;
        a[tt][0] = *(const f16x8*)(ar);
        a[tt][1] = *(const f16x8*)(ar + 8);
        c[tt] = *(const f16x8*)(inp_h + ((b0 * 8 + X) * 8 + Y) * 32 + quad * 8);
    }

    __syncthreads();   // drains vmcnt -> LDS DMA complete

    // ---- K-loop: 16 steps per wave; bfrag shared by 4 b-tiles ----
    f32x4 acc[4] = { {0,0,0,0}, {0,0,0,0}, {0,0,0,0}, {0,0,0,0} };
    const f16* wl = &Wl[khalf * 16 * 512 + m * 32 + quad * 8];
    f16x8 bfrag = *(const f16x8*)(wl);
    #pragma unroll
    for (int kbl = 0; kbl < 16; ++kbl) {
        const f16x8 bcur = bfrag;
        if (kbl < 15)
            bfrag = *(const f16x8*)(wl + (kbl + 1) * 512);   // prefetch next
        #pragma unroll
        for (int tt = 0; tt < 4; ++tt) {
            const f16x8 af = c[tt] * a[tt][kbl >> 3][kbl & 7];
            acc[tt] = __builtin_amdgcn_mfma_f32_16x16x32_f16(af, bcur, acc[tt], 0, 0, 0);
        }
    }

    // ---- combine K-halves via LDS (8 KB in Wl), then store ----
    __syncthreads();                       // all waves done reading Wl
    float* xbuf = (float*)Wl;              // [wset*64+lane][16]
    if (khalf == 1) {
        #pragma unroll
        for (int tt = 0; tt < 4; ++tt)
            *(f32x4*)(&xbuf[(wset * 64 + lane) * 16 + tt * 4]) = acc[tt];
    }
    __syncthreads();
    if (khalf == 0) {
        const float bv = bias[dxdy * 16 + m];
        #pragma unroll
        for (int tt = 0; tt < 4; ++tt) {
            const f32x4 part = *(const f32x4*)(&xbuf[(wset * 64 + lane) * 16 + tt * 4]);
            #pragma unroll
            for (int r = 0; r < 4; ++r) {
                const int b = (wset * 4 + tt) * 16 + quad * 4 + r;
                out[((size_t)b * 4096 + bid) * 16 + m] = acc[tt][r] + part[r] + bv;
            }
        }
    }
}

extern "C" void kernel_launch(void* const* d_in, const int* in_sizes, int n_in,
                              void* d_out, int out_size, void* d_ws, size_t ws_size,
                              hipStream_t stream)
{
    const float* inp  = (const float*)d_in[0];  // (128,8,8,32)
    const float* W    = (const float*)d_in[1];  // (15,15,16,32,32)
    const float* bias = (const float*)d_in[2];  // (15,15,16)
    float* out = (float*)d_out;

    f16* W_h   = (f16*)d_ws;                         // 7,372,800 halves
    f16* inp_h = (f16*)d_ws + (size_t)WGRAN * 8;     //   262,144 halves

    hipLaunchKernelGGL(convert_kernel, dim3((WGRAN + IGRAN) / 256), dim3(256), 0,
                       stream, W, inp, W_h, inp_h);
    hipLaunchKernelGGL(rel_mfma4, dim3(4096), dim3(256), 32768, stream,
                       W_h, inp_h, bias, out);
}